// Round 10
// baseline (128.054 us; speedup 1.0000x reference)
//
#include <hip/hip_runtime.h>
#include <stdint.h>

// N=65536 points, M=1024 gaussians, D=2, C=3, K=10
#define MG 1024
#define KTOP 10
#define EPSF 1e-6f
// 48 x 24 spatial cells: lambda = N/NCELL ~ 56.9 points/cell
#define CX 48
#define CY 24
#define NCELL (CX * CY)       // 1152
#define CAP 80                // points r<CAP stored per cell; r in [64,80) -> chunk-1 block
#define OVB 2                 // overflow blocks for r>=CAP (couple of points at most)
#define OVCAP (OVB * 64)

typedef unsigned long long u64;
typedef unsigned short u16;

__device__ __forceinline__ int cell_of(float x0, float x1) {
    int ix = (int)(x0 * CX); ix = ix < 0 ? 0 : (ix > CX - 1 ? CX - 1 : ix);
    int iy = (int)(x1 * CY); iy = iy < 0 ? 0 : (iy > CY - 1 ? CY - 1 : iy);
    return iy * CX + ix;
}

// Bucket scatter + dual duty: first MG threads also precompute gaussian records
// (fold Sigma^-1) so k_main staging is a pure copy (no rcp chains per wave).
__global__ __launch_bounds__(256) void k_bucket(
    const float* __restrict__ x, const float* __restrict__ mus,
    const float* __restrict__ covs,
    uint32_t* __restrict__ counts, uint32_t* __restrict__ ovc,
    u16* __restrict__ ovlist, u16* __restrict__ buckets,
    float4* __restrict__ grec, float* __restrict__ grecC, int N)
{
    const int n = blockIdx.x * 256 + threadIdx.x;
    if (n < MG) {
        const float4 cv = ((const float4*)covs)[n];
        const float2 mu = ((const float2*)mus)[n];
        const float inv = 1.0f / (cv.x * cv.w - cv.y * cv.z);
        grec[n]  = make_float4(mu.x, mu.y, -0.5f * cv.w * inv, cv.y * inv);
        grecC[n] = -0.5f * cv.x * inv;
    }
    if (n >= N) return;
    const float2 xv = ((const float2*)x)[n];
    const int c = cell_of(xv.x, xv.y);
    const uint32_t r = atomicAdd(&counts[c], 1u);
    if (r < CAP) {
        buckets[c * CAP + r] = (u16)n;
    } else {
        const uint32_t o = atomicAdd(ovc, 1u);
        if (o < OVCAP) ovlist[o] = (u16)n;
    }
}

// Main: 1 block = 1 wave. Block ranges:
//   [0, OVB)                : ovlist points (virtually never nonempty; few distinct pts)
//   [OVB, OVB+NCELL)        : chunk-0 of cell c = points 0..min(cnt,64)  (util ~88%)
//   [OVB+NCELL, OVB+2NCELL) : chunk-1 of cell c = points 64..min(cnt,80) (~17% live, coherent)
// Full 1024-gaussian scan per wave; screened bit-exact u64 top-10 (float screen uses
// >= so exact-value ties with index tie-break still enter the network).
__global__ __launch_bounds__(64, 2) void k_main(
    const float* __restrict__ x, const float* __restrict__ cols,
    const float4* __restrict__ grec, const float* __restrict__ grecC,
    const uint32_t* __restrict__ counts, const uint32_t* __restrict__ ovc,
    const u16* __restrict__ ovlist, const u16* __restrict__ buckets,
    float* __restrict__ out, int N)
{
    __shared__ float4 garr[MG];                 // mux, muy, A, B  (16 KB)
    __shared__ __align__(16) float garrC[MG];   // C               (4 KB)

    const int lane = threadIdx.x;
    const int b = blockIdx.x;

    int p = -1;
    if (b < OVB) {
        const uint32_t oc = min(ovc[0], (uint32_t)OVCAP);
        const uint32_t i = (uint32_t)(b * 64 + lane);
        if (i < oc) p = (int)ovlist[i];
        if (__ballot(p >= 0) == 0ull) return;   // usually: exit before staging
    } else if (b < OVB + NCELL) {
        const int c = b - OVB;
        const uint32_t cnt = min(counts[c], (uint32_t)64);
        if (cnt == 0u) return;
        if ((uint32_t)lane < cnt) p = (int)buckets[c * CAP + lane];
    } else {
        const int c = b - OVB - NCELL;
        const uint32_t cnt = min(counts[c], (uint32_t)CAP);
        if (cnt <= 64u) return;                 // ~83%: exit before staging
        if ((uint32_t)(64 + lane) < cnt) p = (int)buckets[c * CAP + 64 + lane];
    }
    const bool valid = (p >= 0);
    const int p0lane = __shfl(p, 0);            // unconditional cross-lane op
    const int pp = valid ? p : p0lane;          // idle lanes mirror lane 0's point

    // ---- Stage gaussian records: pure 20KB copy (records precomputed in k_bucket) ----
    #pragma unroll
    for (int k = 0; k < MG / 64; ++k) {
        const int m = lane + 64 * k;
        garr[m]  = grec[m];
        garrC[m] = grecC[m];
    }
    __syncthreads();

    const float2 xv = ((const float2*)x)[pp];
    const float x0 = xv.x, x1 = xv.y;

    u64 topk[KTOP];
    const u64 SENT = ((u64)0x007FFFFFull) << 10;   // packed -inf, index 1023
    #pragma unroll
    for (int j = 0; j < KTOP; ++j) topk[j] = SENT;
    float thr = __uint_as_float(0xff800000u);      // -inf: warmup always passes screen

    auto net_insert = [&](u64 key) {
        bool c[KTOP];
        #pragma unroll
        for (int j = 0; j < KTOP; ++j) c[j] = topk[j] >= key;
        #pragma unroll
        for (int j = KTOP - 1; j >= 1; --j)
            topk[j] = c[j] ? topk[j] : (c[j - 1] ? key : topk[j - 1]);
        topk[0] = c[0] ? topk[0] : key;
    };
    auto ins = [&](float q, int m) {
        if (__any(q >= thr)) {
            const uint32_t bb = __float_as_uint(q);
            const uint32_t msk = (uint32_t)((int32_t)bb >> 31) | 0x80000000u;
            net_insert(((u64)(bb ^ msk) << 10) | (u64)(MG - 1 - m));
            const uint32_t kb = (uint32_t)(topk[KTOP - 1] >> 10);
            const uint32_t db = ((int32_t)kb < 0) ? (kb ^ 0x80000000u) : ~kb;
            thr = __uint_as_float(db);             // value of current 10th
        }
    };

    #pragma unroll 2
    for (int m = 0; m < MG; m += 4) {
        const float4 g0 = garr[m], g1 = garr[m + 1], g2 = garr[m + 2], g3 = garr[m + 3];
        const float4 c4 = *(const float4*)&garrC[m];
        const float dx0 = x0 - g0.x, dy0 = x1 - g0.y;
        const float dx1 = x0 - g1.x, dy1 = x1 - g1.y;
        const float dx2 = x0 - g2.x, dy2 = x1 - g2.y;
        const float dx3 = x0 - g3.x, dy3 = x1 - g3.y;
        const float q0 = fmaf(fmaf(g0.z, dx0, g0.w * dy0), dx0, c4.x * (dy0 * dy0));
        const float q1 = fmaf(fmaf(g1.z, dx1, g1.w * dy1), dx1, c4.y * (dy1 * dy1));
        const float q2 = fmaf(fmaf(g2.z, dx2, g2.w * dy2), dx2, c4.z * (dy2 * dy2));
        const float q3 = fmaf(fmaf(g3.z, dx3, g3.w * dy3), dx3, c4.w * (dy3 * dy3));
        const float qm = fmaxf(fmaxf(q0, q1), fmaxf(q2, q3));
        if (__any(qm >= thr)) {
            ins(q0, m); ins(q1, m + 1); ins(q2, m + 2); ins(q3, m + 3);
        }
    }

    // ---- Epilogue: decode exact q from keys; colors gathered from global (L2-hot) ----
    float vsum = 0.0f, rc = 0.0f, gc = 0.0f, bc = 0.0f;
    #pragma unroll
    for (int j = 0; j < KTOP; ++j) {
        const u64 key = topk[j];
        const int m = (MG - 1) - (int)(key & 1023u);
        const uint32_t kb = (uint32_t)(key >> 10);
        const uint32_t bb = ((int32_t)kb < 0) ? (kb ^ 0x80000000u) : ~kb;
        const float v = __expf(__uint_as_float(bb));
        vsum += v;
        rc = fmaf(v, cols[3 * m + 0], rc);
        gc = fmaf(v, cols[3 * m + 1], gc);
        bc = fmaf(v, cols[3 * m + 2], bc);
    }
    const float s = 1.0f / (vsum + EPSF);
    if (valid) {
        out[pp * 3 + 0] = rc * s;
        out[pp * 3 + 1] = gc * s;
        out[pp * 3 + 2] = bc * s;
    }
}

extern "C" void kernel_launch(void* const* d_in, const int* in_sizes, int n_in,
                              void* d_out, int out_size, void* d_ws, size_t ws_size,
                              hipStream_t stream) {
    const float* x    = (const float*)d_in[0];
    const float* mus  = (const float*)d_in[1];
    const float* covs = (const float*)d_in[2];
    const float* cols = (const float*)d_in[3];
    float* out = (float*)d_out;
    const int N = in_sizes[0] / 2;

    // ws layout: counts 4608B | ovc 16B | ovlist 256B | grec 16KB | grecC 4KB | buckets 180KB
    uint32_t* counts = (uint32_t*)d_ws;                       // 1152 * 4
    uint32_t* ovc    = counts + NCELL;                        // 16 B
    u16*      ovlist = (u16*)(ovc + 4);                       // 256 B
    float4*   grec   = (float4*)((char*)(ovlist + OVCAP));    // 16 KB (16B-aligned: offset 4880? ensure alignment)
    // fix alignment: place grec on a 16B boundary
    {
        uintptr_t a = (uintptr_t)(ovlist + OVCAP);
        a = (a + 15) & ~(uintptr_t)15;
        grec = (float4*)a;
    }
    float*    grecC  = (float*)(grec + MG);                   // 4 KB
    u16*      buckets= (u16*)(grecC + MG);                    // 1152*80*2 = 184320 B
    const size_t need = ((char*)(buckets + NCELL * CAP)) - (char*)d_ws;

    if (ws_size >= need) {
        hipMemsetAsync(counts, 0, NCELL * sizeof(uint32_t) + 16, stream);  // counts + ovc
        k_bucket<<<(N + 255) / 256, 256, 0, stream>>>(x, mus, covs, counts, ovc,
                                                      ovlist, buckets, grec, grecC, N);
        k_main<<<OVB + 2 * NCELL, 64, 0, stream>>>(x, cols, grec, grecC,
                                                   counts, ovc, ovlist, buckets, out, N);
    }
    // (ws_size is known >=258KB from prior rounds; need ~210KB. No fallback path needed,
    //  but guard prevents OOB if assumptions break — output would then fail loudly via absmax.)
}

// Round 11
// 108.606 us; speedup vs baseline: 1.1791x; 1.1791x over previous
//
#include <hip/hip_runtime.h>
#include <stdint.h>

// N=65536 points, M=1024 gaussians, D=2, C=3, K=10
#define MG 1024
#define KTOP 10
#define EPSF 1e-6f
// 24 x 16 spatial cells: lambda = 65536/384 ~ 170.7 points/cell
#define CXc 24
#define CYc 16
#define NCELL (CXc * CYc)     // 384
#define CAP 224               // +4 sigma of Poisson(171); r>=CAP -> exact overflow path
#define OVB 2
#define OVCAP (OVB * 64)
// cell half-diagonal, rounded UP: sqrt((0.5/24)^2 + (0.5/16)^2) = 0.037558
#define RHO 0.03757f

typedef unsigned long long u64;
typedef unsigned short u16;

__device__ __forceinline__ int cell_of(float x0, float x1) {
    int ix = (int)(x0 * CXc); ix = ix < 0 ? 0 : (ix > CXc - 1 ? CXc - 1 : ix);
    int iy = (int)(x1 * CYc); iy = iy < 0 ? 0 : (iy > CYc - 1 ? CYc - 1 : iy);
    return iy * CXc + ix;
}

// Fused prep: blocks [0,256) = bucket scatter + grec precompute (as R10).
// Blocks [256,352) = prefilter: 4 waves/block, one wave per cell. Per cell:
// exact-safe candidate mask. Bounds (real analysis, margins cover float error):
//   q_m(x) <= q_c + |S dc| rho            =: U_m   (S = Sigma^-1, dc = xc - mu)
//   q_m(x) >= q_c - |S dc| rho - l rho²/2 =: D_m   (l = trace(S) >= lambda_max)
// L = 10th-largest D over all 1024 -> drop m iff U_m < L: then 10 gaussians are
// STRICTLY greater at every x in the cell -> m never in any top-10 (tie-safe).
__global__ __launch_bounds__(256) void k_prep(
    const float* __restrict__ x, const float* __restrict__ mus,
    const float* __restrict__ covs,
    uint32_t* __restrict__ counts, uint32_t* __restrict__ ovc,
    u16* __restrict__ ovlist, u16* __restrict__ buckets,
    float4* __restrict__ grec, float* __restrict__ grecC,
    u16* __restrict__ mask16, int N)
{
    const int t = threadIdx.x, blk = blockIdx.x;
    if (blk < 256) {
        const int n = blk * 256 + t;
        if (n < MG) {
            const float4 cv = ((const float4*)covs)[n];
            const float2 mu = ((const float2*)mus)[n];
            const float inv = 1.0f / (cv.x * cv.w - cv.y * cv.z);
            grec[n]  = make_float4(mu.x, mu.y, -0.5f * cv.w * inv, cv.y * inv);
            grecC[n] = -0.5f * cv.x * inv;
        }
        if (n >= N) return;
        const float2 xv = ((const float2*)x)[n];
        const int c = cell_of(xv.x, xv.y);
        const uint32_t r = atomicAdd(&counts[c], 1u);
        if (r < CAP) buckets[c * CAP + r] = (u16)n;
        else { const uint32_t o = atomicAdd(ovc, 1u); if (o < OVCAP) ovlist[o] = (u16)n; }
        return;
    }
    // ---- prefilter: one wave per cell ----
    const int lane = t & 63;
    const int c = (blk - 256) * 4 + (t >> 6);
    const float cx = ((float)(c % CXc) + 0.5f) / (float)CXc;
    const float cy = ((float)(c / CXc) + 0.5f) / (float)CYc;
    const float INF = __builtin_huge_valf();

    float D10[KTOP], Uv[16];
    #pragma unroll
    for (int i = 0; i < KTOP; ++i) D10[i] = -INF;

    #pragma unroll
    for (int j = 0; j < 16; ++j) {
        const int m = lane * 16 + j;
        const float4 cv = ((const float4*)covs)[m];
        const float2 mu = ((const float2*)mus)[m];
        const float inv = 1.0f / (cv.x * cv.w - cv.y * cv.z);
        const float A = -0.5f * cv.w * inv, B = cv.y * inv, Cc = -0.5f * cv.x * inv;
        const float dx = cx - mu.x, dy = cy - mu.y;
        const float qc = fmaf(fmaf(A, dx, B * dy), dx, Cc * (dy * dy));
        const float S00 = -2.0f * A, S01 = -B, S11 = -2.0f * Cc;
        const float sx = S00 * dx + S01 * dy, sy = S01 * dx + S11 * dy;
        const float slack = sqrtf(fmaf(sx, sx, sy * sy)) * RHO;
        const float lr2 = 0.5f * (S00 + S11) * (RHO * RHO);
        const float eps = 1e-3f * (1.0f + fabsf(qc) + slack);
        Uv[j] = qc + slack + eps;
        const float D = qc - slack - lr2 - eps;
        bool cg[KTOP];
        #pragma unroll
        for (int i = 0; i < KTOP; ++i) cg[i] = D10[i] >= D;
        #pragma unroll
        for (int i = KTOP - 1; i >= 1; --i)
            D10[i] = cg[i] ? D10[i] : (cg[i - 1] ? D : D10[i - 1]);
        D10[0] = cg[0] ? D10[0] : D;
    }
    // butterfly merge of sorted-descending 10-lists across 64 lanes
    #pragma unroll
    for (int s = 1; s < 64; s <<= 1) {
        float ob[KTOP], na[KTOP];
        #pragma unroll
        for (int i = 0; i < KTOP; ++i) ob[i] = __shfl_xor(D10[i], s);
        #pragma unroll
        for (int i = 0; i < KTOP; ++i) {
            float best = -INF;
            #pragma unroll
            for (int j = 0; j <= i + 1 && j <= KTOP; ++j) {
                const int l = i + 1 - j;
                if (l > KTOP) continue;
                const float av = (j == 0) ? INF : D10[j - 1];
                const float bv = (l == 0) ? INF : ob[l - 1];
                best = fmaxf(best, fminf(av, bv));
            }
            na[i] = best;
        }
        #pragma unroll
        for (int i = 0; i < KTOP; ++i) D10[i] = na[i];
    }
    const float L = D10[KTOP - 1];
    uint32_t w = 0;
    #pragma unroll
    for (int j = 0; j < 16; ++j) if (Uv[j] >= L) w |= (1u << j);
    mask16[c * 64 + lane] = (u16)w;
}

// Main: 1 block = 1 wave. Blocks [0,OVB): overflow points, full 1024 scan from
// global grec (virtually never live). Else block (b-OVB) = chunk (b-OVB)&3 of
// cell (b-OVB)>>2. Wave compacts its cell's surviving records (mask) into LDS
// (ballot-prefix, ascending m), then screened bit-exact u64 top-10 over ~110
// candidates instead of 1024. Selection provably identical to full scan.
__global__ __launch_bounds__(64) void k_main(
    const float* __restrict__ x, const float* __restrict__ cols,
    const float4* __restrict__ grec, const float* __restrict__ grecC,
    const uint32_t* __restrict__ counts, const uint32_t* __restrict__ ovc,
    const u16* __restrict__ ovlist, const u16* __restrict__ buckets,
    const u16* __restrict__ mask16, float* __restrict__ out, int N)
{
    __shared__ float4 l4[MG + 4];
    __shared__ __align__(16) float lC[MG + 4];
    __shared__ __align__(16) uint32_t lM[MG + 4];

    const int lane = threadIdx.x;
    const int b = blockIdx.x;

    int p = -1, c = -1;
    bool full = false;
    if (b < OVB) {
        const uint32_t oc = min(ovc[0], (uint32_t)OVCAP);
        const uint32_t i = (uint32_t)(b * 64 + lane);
        if (i < oc) p = (int)ovlist[i];
        if (__ballot(p >= 0) == 0ull) return;
        full = true;
    } else {
        const int bc = b - OVB;
        c = bc >> 2;
        const int chunk = bc & 3;
        const int cnt = (int)min(counts[c], (uint32_t)CAP);
        if (chunk * 64 >= cnt) return;
        const int i = chunk * 64 + lane;
        if (i < cnt) p = (int)buckets[c * CAP + i];
    }
    const bool valid = (p >= 0);
    const int p0lane = __shfl(p, 0);
    const int pp = valid ? p : p0lane;

    const float2 xv = ((const float2*)x)[pp];
    const float x0 = xv.x, x1 = xv.y;

    u64 topk[KTOP];
    const u64 SENT = ((u64)0x007FFFFFull) << 10;
    #pragma unroll
    for (int j = 0; j < KTOP; ++j) topk[j] = SENT;
    float thr = __uint_as_float(0xff800000u);

    auto net_insert = [&](u64 key) {
        bool cg[KTOP];
        #pragma unroll
        for (int j = 0; j < KTOP; ++j) cg[j] = topk[j] >= key;
        #pragma unroll
        for (int j = KTOP - 1; j >= 1; --j)
            topk[j] = cg[j] ? topk[j] : (cg[j - 1] ? key : topk[j - 1]);
        topk[0] = cg[0] ? topk[0] : key;
    };
    auto ins = [&](float q, int m) {
        if (__any(q >= thr)) {
            const uint32_t bb = __float_as_uint(q);
            const uint32_t msk = (uint32_t)((int32_t)bb >> 31) | 0x80000000u;
            net_insert(((u64)(bb ^ msk) << 10) | (u64)(MG - 1 - m));
            const uint32_t kb = (uint32_t)(topk[KTOP - 1] >> 10);
            const uint32_t db = ((int32_t)kb < 0) ? (kb ^ 0x80000000u) : ~kb;
            thr = __uint_as_float(db);
        }
    };

    if (!full) {
        // ---- compact surviving records into LDS ----
        uint32_t word = (lane < 32) ? ((const uint32_t*)mask16)[c * 32 + lane] : 0u;
        const int pc = __popc(word);
        int incl = pc;
        #pragma unroll
        for (int off = 1; off < 64; off <<= 1) {
            const int v = __shfl_up(incl, off);
            if (lane >= off) incl += v;
        }
        int slot = incl - pc;
        const int nsur = __shfl(incl, 63);
        uint32_t mw = word;
        while (mw) {
            const int bit = __ffs(mw) - 1;
            mw &= mw - 1;
            const int m = lane * 32 + bit;
            l4[slot] = grec[m];
            lC[slot] = grecC[m];
            lM[slot] = (uint32_t)m;
            slot++;
        }
        const int pad = (4 - (nsur & 3)) & 3;
        if (lane < pad) {   // sentinel: q evaluates to -inf, never selected
            l4[nsur + lane] = make_float4(3e30f, 3e30f, -1.0f, 0.0f);
            lC[nsur + lane] = -1.0f;
            lM[nsur + lane] = 0u;
        }
        const int ntot = nsur + pad;
        __syncthreads();

        for (int i = 0; i < ntot; i += 4) {
            const float4 g0 = l4[i], g1 = l4[i + 1], g2 = l4[i + 2], g3 = l4[i + 3];
            const float4 c4 = *(const float4*)&lC[i];
            const uint4  m4 = *(const uint4*)&lM[i];
            const float dx0 = x0 - g0.x, dy0 = x1 - g0.y;
            const float dx1 = x0 - g1.x, dy1 = x1 - g1.y;
            const float dx2 = x0 - g2.x, dy2 = x1 - g2.y;
            const float dx3 = x0 - g3.x, dy3 = x1 - g3.y;
            const float q0 = fmaf(fmaf(g0.z, dx0, g0.w * dy0), dx0, c4.x * (dy0 * dy0));
            const float q1 = fmaf(fmaf(g1.z, dx1, g1.w * dy1), dx1, c4.y * (dy1 * dy1));
            const float q2 = fmaf(fmaf(g2.z, dx2, g2.w * dy2), dx2, c4.z * (dy2 * dy2));
            const float q3 = fmaf(fmaf(g3.z, dx3, g3.w * dy3), dx3, c4.w * (dy3 * dy3));
            const float qm = fmaxf(fmaxf(q0, q1), fmaxf(q2, q3));
            if (__any(qm >= thr)) {
                ins(q0, (int)m4.x); ins(q1, (int)m4.y);
                ins(q2, (int)m4.z); ins(q3, (int)m4.w);
            }
        }
    } else {
        for (int m = 0; m < MG; m += 4) {
            const float4 g0 = grec[m], g1 = grec[m + 1], g2 = grec[m + 2], g3 = grec[m + 3];
            const float4 c4 = *(const float4*)&grecC[m];
            const float dx0 = x0 - g0.x, dy0 = x1 - g0.y;
            const float dx1 = x0 - g1.x, dy1 = x1 - g1.y;
            const float dx2 = x0 - g2.x, dy2 = x1 - g2.y;
            const float dx3 = x0 - g3.x, dy3 = x1 - g3.y;
            const float q0 = fmaf(fmaf(g0.z, dx0, g0.w * dy0), dx0, c4.x * (dy0 * dy0));
            const float q1 = fmaf(fmaf(g1.z, dx1, g1.w * dy1), dx1, c4.y * (dy1 * dy1));
            const float q2 = fmaf(fmaf(g2.z, dx2, g2.w * dy2), dx2, c4.z * (dy2 * dy2));
            const float q3 = fmaf(fmaf(g3.z, dx3, g3.w * dy3), dx3, c4.w * (dy3 * dy3));
            const float qm = fmaxf(fmaxf(q0, q1), fmaxf(q2, q3));
            if (__any(qm >= thr)) {
                ins(q0, m); ins(q1, m + 1); ins(q2, m + 2); ins(q3, m + 3);
            }
        }
    }

    // ---- Epilogue: decode exact q from keys; colors gathered from global ----
    float vsum = 0.0f, rc = 0.0f, gc = 0.0f, bc = 0.0f;
    #pragma unroll
    for (int j = 0; j < KTOP; ++j) {
        const u64 key = topk[j];
        const int m = (MG - 1) - (int)(key & 1023u);
        const uint32_t kb = (uint32_t)(key >> 10);
        const uint32_t bb = ((int32_t)kb < 0) ? (kb ^ 0x80000000u) : ~kb;
        const float v = __expf(__uint_as_float(bb));
        vsum += v;
        rc = fmaf(v, cols[3 * m + 0], rc);
        gc = fmaf(v, cols[3 * m + 1], gc);
        bc = fmaf(v, cols[3 * m + 2], bc);
    }
    const float s = 1.0f / (vsum + EPSF);
    if (valid) {
        out[pp * 3 + 0] = rc * s;
        out[pp * 3 + 1] = gc * s;
        out[pp * 3 + 2] = bc * s;
    }
}

extern "C" void kernel_launch(void* const* d_in, const int* in_sizes, int n_in,
                              void* d_out, int out_size, void* d_ws, size_t ws_size,
                              hipStream_t stream) {
    const float* x    = (const float*)d_in[0];
    const float* mus  = (const float*)d_in[1];
    const float* covs = (const float*)d_in[2];
    const float* cols = (const float*)d_in[3];
    float* out = (float*)d_out;
    const int N = in_sizes[0] / 2;

    // ws layout (~244 KB; >=258 KB proven available in R9/R10):
    uint32_t* counts = (uint32_t*)d_ws;                   // 384*4 = 1536 B
    uint32_t* ovc    = counts + NCELL;                    // 16 B
    u16*      ovlist = (u16*)(ovc + 4);                   // 256 B
    uintptr_t a = (uintptr_t)(ovlist + OVCAP);
    a = (a + 15) & ~(uintptr_t)15;
    float4*   grec   = (float4*)a;                        // 16 KB
    float*    grecC  = (float*)(grec + MG);               // 4 KB
    u16*      buckets= (u16*)(grecC + MG);                // 384*224*2 = 172032 B
    u16*      mask16 = buckets + NCELL * CAP;             // 384*64*2 = 49152 B
    const size_t need = ((char*)(mask16 + NCELL * 64)) - (char*)d_ws;

    if (ws_size >= need) {
        hipMemsetAsync(counts, 0, NCELL * sizeof(uint32_t) + 16, stream);
        k_prep<<<256 + NCELL / 4, 256, 0, stream>>>(x, mus, covs, counts, ovc,
                                                    ovlist, buckets, grec, grecC,
                                                    mask16, N);
        k_main<<<OVB + 4 * NCELL, 64, 0, stream>>>(x, cols, grec, grecC,
                                                   counts, ovc, ovlist, buckets,
                                                   mask16, out, N);
    }
}